// Round 3
// baseline (548.156 us; speedup 1.0000x reference)
//
#include <hip/hip_runtime.h>
#include <hip/hip_bf16.h>
#include <math.h>

#define N_NODES 20000
#define N_EDGES 320000
#define F_IN    127
#define ETOT    (N_EDGES + N_NODES)
#define SCAN_B  ((N_NODES + 255) / 256)   // 79

typedef __attribute__((ext_vector_type(8))) short short8;
typedef __attribute__((ext_vector_type(4))) float f32x4;

__device__ inline unsigned short f2bf(float f) {
  union { float f; unsigned int u; } v; v.f = f;
  unsigned int u = v.u;
  unsigned int r = (u + 0x7fffu + ((u >> 16) & 1u)) >> 16;
  return (unsigned short)r;
}
__device__ inline float bf2f(unsigned short b) {
  union { unsigned int u; float f; } v; v.u = ((unsigned int)b) << 16;
  return v.f;
}
__device__ inline float bflo(unsigned int v) {
  union { unsigned int u; float f; } x; x.u = v << 16; return x.f;
}
__device__ inline float bfhi(unsigned int v) {
  union { unsigned int u; float f; } x; x.u = v & 0xffff0000u; return x.f;
}

// ---------------- CSR build ----------------
__global__ void k_init(int* __restrict__ counts, float* __restrict__ stats,
                       int* __restrict__ ghist, int* __restrict__ row_start) {
  int i = blockIdx.x * blockDim.x + threadIdx.x;
  if (i < N_NODES) counts[i] = 1;   // self loop pre-counted
  if (i < 2048) stats[i] = 0.f;
  if (i < 64) ghist[i] = 0;
  if (i == 0) row_start[N_NODES] = ETOT;   // total is a compile-time constant
}

__global__ void k_hist(const int* __restrict__ ei, int* __restrict__ counts) {
  int e = blockIdx.x * blockDim.x + threadIdx.x;
  if (e < N_EDGES) atomicAdd(&counts[ei[N_EDGES + e]], 1);
}

// ---- multi-block scan, phase 1: per-block exclusive scan + block sums ----
// Also accumulates the 64-bucket degree histogram (deg = counts[i], self loop incl).
__global__ __launch_bounds__(256) void k_scan1(const int* __restrict__ counts,
                                               int* __restrict__ escan,
                                               int* __restrict__ bsum,
                                               int* __restrict__ ghist) {
  __shared__ int sh[256];
  int t = threadIdx.x;
  int i = blockIdx.x * 256 + t;
  int c = (i < N_NODES) ? counts[i] : 0;
  if (i < N_NODES) atomicAdd(&ghist[min(c, 63)], 1);
  sh[t] = c;
  __syncthreads();
#pragma unroll
  for (int off = 1; off < 256; off <<= 1) {
    int u = (t >= off) ? sh[t - off] : 0;
    __syncthreads();
    sh[t] += u;
    __syncthreads();
  }
  if (i < N_NODES) escan[i] = sh[t] - c;
  if (t == 255) bsum[blockIdx.x] = sh[255];
}

// ---- phase 2 (tiny, 1 block): scan block sums + degree-bucket bases ----
__global__ __launch_bounds__(128) void k_scan2(const int* __restrict__ bsum,
                                               int* __restrict__ bbase,
                                               const int* __restrict__ ghist,
                                               int* __restrict__ gcur) {
  __shared__ int sh[128];
  int t = threadIdx.x;
  int v = (t < SCAN_B) ? bsum[t] : 0;
  sh[t] = v;
  __syncthreads();
#pragma unroll
  for (int off = 1; off < 128; off <<= 1) {
    int u = (t >= off) ? sh[t - off] : 0;
    __syncthreads();
    sh[t] += u;
    __syncthreads();
  }
  if (t < SCAN_B) bbase[t] = sh[t] - v;
  __syncthreads();
  int g = (t < 64) ? ghist[t] : 0;
  sh[t] = g;
  __syncthreads();
#pragma unroll
  for (int off = 1; off < 64; off <<= 1) {
    int u = (t >= off) ? sh[t - off] : 0;
    __syncthreads();
    sh[t] += u;
    __syncthreads();
  }
  if (t < 64) gcur[t] = sh[t] - g;
}

// ---- phase 3: finalize row_start / self-loop / write cursors + perm scatter ----
__global__ __launch_bounds__(256) void k_scan3(const int* __restrict__ counts,
                                               const int* __restrict__ escan,
                                               const int* __restrict__ bbase,
                                               int* __restrict__ row_start,
                                               int* __restrict__ wcur,
                                               int* __restrict__ srcs,
                                               int* __restrict__ gcur,
                                               int* __restrict__ perm) {
  int i = blockIdx.x * 256 + threadIdx.x;
  if (i >= N_NODES) return;
  int rs = bbase[blockIdx.x] + escan[i];
  row_start[i] = rs;
  srcs[rs] = i;          // self loop at slot 0 of each row
  wcur[i] = rs + 1;
  int d = min(counts[i], 63);
  int p = atomicAdd(&gcur[d], 1);
  perm[p] = i;           // degree-bucketed permutation (within-bucket order arbitrary)
}

__global__ void k_scatter(const int* __restrict__ ei, int* __restrict__ wcur,
                          int* __restrict__ srcs) {
  int e = blockIdx.x * blockDim.x + threadIdx.x;
  if (e < N_EDGES) {
    int s = ei[e], d = ei[N_EDGES + e];
    int p = atomicAdd(&wcur[d], 1);
    srcs[p] = s;
  }
}

// ---------------- input concat + weight cast/transpose (merged) ----------------
__global__ void k_prep(const float* __restrict__ X, const float* __restrict__ pos,
                       unsigned short* __restrict__ xbf,
                       const float* __restrict__ W1, const float* __restrict__ W2,
                       const float* __restrict__ oW,
                       unsigned short* __restrict__ W1t, unsigned short* __restrict__ W2t,
                       unsigned short* __restrict__ oWt) {
  int i = blockIdx.x * blockDim.x + threadIdx.x;
  if (i < N_NODES * 128) { int n = i >> 7, k = i & 127; xbf[i] = f2bf((k < F_IN) ? X[n * F_IN + k] : pos[n]); }
  if (i < 128 * 512) { int r = i >> 9, c = i & 511; W1t[c * 128 + r] = f2bf(W1[i]); }
  if (i < 512 * 512) { int r = i >> 9, c = i & 511; W2t[c * 512 + r] = f2bf(W2[i]); }
  if (i < 512 * 256) { int r = i >> 8, c = i & 255; oWt[c * 512 + r] = f2bf(oW[i]); }
}

// ---------------- bf16 MFMA GEMM: C = A[M,K] @ Bt[Nc,K]^T (+bias) ----------------
// 128x128 tile, 256 thr (4 waves, 2x2), each wave 64x64 = 4x4 MFMA 16x16x32.
__global__ __launch_bounds__(256) void k_mgemm(
    const unsigned short* __restrict__ A, const unsigned short* __restrict__ Bt,
    const float* __restrict__ bias, float* __restrict__ Cf,
    unsigned short* __restrict__ Cbf, int M, int Nc, int K)
{
  __shared__ unsigned short As[128 * 32];
  __shared__ unsigned short Bs[128 * 32];
  int t = threadIdx.x;
  int w = t >> 6, l = t & 63;
  int wr = w >> 1, wc = w & 1;
  int lane15 = l & 15, kq = l >> 4;
  int m0 = blockIdx.y * 128, n0 = blockIdx.x * 128;
  f32x4 acc[4][4] = {};

  int cA = 2 * w;
  int rowA0 = 16 * cA + (l >> 2);
  int koff = (l & 3) * 8;

  for (int k0 = 0; k0 < K; k0 += 32) {
    __syncthreads();
#pragma unroll
    for (int cc = 0; cc < 2; ++cc) {
      int c = cA + cc;
      int row = rowA0 + 16 * cc;
      const unsigned short* g = A + (size_t)min(m0 + row, M - 1) * K + k0 + koff;
      __builtin_amdgcn_global_load_lds(
          (const __attribute__((address_space(1))) unsigned int*)g,
          (__attribute__((address_space(3))) unsigned int*)&As[c * 512], 16, 0, 0);
      const unsigned short* gb = Bt + (size_t)(n0 + row) * K + k0 + koff;
      __builtin_amdgcn_global_load_lds(
          (const __attribute__((address_space(1))) unsigned int*)gb,
          (__attribute__((address_space(3))) unsigned int*)&Bs[c * 512], 16, 0, 0);
    }
    __syncthreads();
    short8 a[4], b[4];
#pragma unroll
    for (int i = 0; i < 4; ++i)
      a[i] = *(const short8*)&As[(wr * 64 + i * 16 + lane15) * 32 + kq * 8];
#pragma unroll
    for (int j = 0; j < 4; ++j)
      b[j] = *(const short8*)&Bs[(wc * 64 + j * 16 + lane15) * 32 + kq * 8];
#pragma unroll
    for (int i = 0; i < 4; ++i)
#pragma unroll
      for (int j = 0; j < 4; ++j)
        acc[i][j] = __builtin_amdgcn_mfma_f32_16x16x32_bf16(a[i], b[j], acc[i][j], 0, 0, 0);
  }
  // epilogue: C/D layout col=lane&15, row=(lane>>4)*4+reg
#pragma unroll
  for (int i = 0; i < 4; ++i) {
#pragma unroll
    for (int j = 0; j < 4; ++j) {
      int col = n0 + wc * 64 + j * 16 + lane15;
      float bv = bias ? bias[col] : 0.f;
#pragma unroll
      for (int r = 0; r < 4; ++r) {
        int row = m0 + wr * 64 + i * 16 + kq * 4 + r;
        if (row < M) {
          float val = acc[i][j][r] + bv;
          if (Cbf) Cbf[(size_t)row * Nc + col] = f2bf(val);
          else     Cf[(size_t)row * Nc + col] = val;
        }
      }
    }
  }
}

// ---------------- attention logit vectors al_s/al_d [N,4], bf16 input ----------------
__global__ __launch_bounds__(256) void k_al(
    const unsigned short* __restrict__ xlbf, const float* __restrict__ a_src,
    const float* __restrict__ a_dst, float* __restrict__ al_s, float* __restrict__ al_d)
{
  int n = blockIdx.x, t = threadIdx.x;
  int h = t >> 6, l = t & 63;
  int c0 = h * 128 + 2 * l;
  unsigned int v = *(const unsigned int*)&xlbf[(size_t)n * 512 + c0];
  float v0 = bflo(v), v1 = bfhi(v);
  float ps = v0 * a_src[c0] + v1 * a_src[c0 + 1];
  float pd = v0 * a_dst[c0] + v1 * a_dst[c0 + 1];
#pragma unroll
  for (int off = 32; off; off >>= 1) { ps += __shfl_down(ps, off); pd += __shfl_down(pd, off); }
  if (l == 0) { al_s[n * 4 + h] = ps; al_d[n * 4 + h] = pd; }
}

// ---------------- edge softmax, single pass, no max-subtraction ----------------
// Softmax is shift-invariant; logits here are O(1) (clamped at 60 for safety,
// self-loop guarantees S>0), so skip the max pass entirely. Writes UNNORMALIZED
// p=exp(lg) head-major pH[h][e] (stream-read by k_agg) and per-node 1/S in rS.
// k_agg multiplies its accumulator by 1/S at the end.
// Block 256 = 4 waves; wave per node, 64 lanes stride edges.
__global__ __launch_bounds__(256) void k_alpha(
    const float* __restrict__ al_s, const float* __restrict__ al_d,
    const int* __restrict__ row_start, const int* __restrict__ srcs,
    float* __restrict__ pH, float* __restrict__ rS)
{
  int w = threadIdx.x >> 6, l = threadIdx.x & 63;
  int n = blockIdx.x * 4 + w;
  if (n >= N_NODES) return;

  int rs = row_start[n];
  int deg = row_start[n + 1] - rs;
  float4 ad4 = *(const float4*)&al_d[n * 4];
  float s0 = 0.f, s1 = 0.f, s2 = 0.f, s3 = 0.f;
  for (int i = l; i < deg; i += 64) {
    int e = rs + i;
    int s = srcs[e];
    float4 as4 = *(const float4*)&al_s[(size_t)s * 4];
    float lg0 = as4.x + ad4.x; lg0 = (lg0 >= 0.f) ? lg0 : 0.2f * lg0;
    float lg1 = as4.y + ad4.y; lg1 = (lg1 >= 0.f) ? lg1 : 0.2f * lg1;
    float lg2 = as4.z + ad4.z; lg2 = (lg2 >= 0.f) ? lg2 : 0.2f * lg2;
    float lg3 = as4.w + ad4.w; lg3 = (lg3 >= 0.f) ? lg3 : 0.2f * lg3;
    float p0 = __expf(fminf(lg0, 60.f));
    float p1 = __expf(fminf(lg1, 60.f));
    float p2 = __expf(fminf(lg2, 60.f));
    float p3 = __expf(fminf(lg3, 60.f));
    pH[0 * ETOT + e] = p0;
    pH[1 * ETOT + e] = p1;
    pH[2 * ETOT + e] = p2;
    pH[3 * ETOT + e] = p3;
    s0 += p0; s1 += p1; s2 += p2; s3 += p3;
  }
#pragma unroll
  for (int off = 32; off; off >>= 1) {
    s0 += __shfl_down(s0, off);
    s1 += __shfl_down(s1, off);
    s2 += __shfl_down(s2, off);
    s3 += __shfl_down(s3, off);
  }
  if (l == 0) {
    rS[n * 4 + 0] = 1.f / (s0 + 1e-16f);
    rS[n * 4 + 1] = 1.f / (s1 + 1e-16f);
    rS[n * 4 + 2] = 1.f / (s2 + 1e-16f);
    rS[n * 4 + 3] = 1.f / (s3 + 1e-16f);
  }
}

// ---------------- GAT aggregate: channel-sliced + deg-sorted ----------------
// Grid (8, 625): blockIdx.x = channel slice (64 ch) -> pinned to one XCD by
// round-robin dispatch; per-XCD gather working set 2.56 MB < 4 MB L2.
// Block 256 = 4 waves; wave = 8 nodes x 8 lanes; lane owns 8 ch (16B uint4
// gather) -> 8 independent gather chains per wave. Nodes taken via deg-sorted
// perm so the 8 nodes of a wave have ~equal degree (uniform trip count).
// Accumulates unnormalized sum(p*x), scales by 1/S at the end.
__global__ __launch_bounds__(256) void k_agg(
    const unsigned short* __restrict__ xlbf, const float* __restrict__ pH,
    const float* __restrict__ rS, const int* __restrict__ row_start,
    const int* __restrict__ srcs, const int* __restrict__ perm,
    const float* __restrict__ bias, float* __restrict__ out)
{
  int slice = blockIdx.x;                 // 0..7
  int t = threadIdx.x;
  int w = t >> 6;                         // wave in block
  int l = t & 63;
  int grp = l >> 3;                       // 0..7 node within wave
  int g = l & 7;                          // lane within group
  int n = perm[(blockIdx.y * 4 + w) * 8 + grp];   // 625*4*8 == 20000 exactly
  int h = slice >> 1;                     // head owning this slice
  int c0 = slice * 64 + g * 8;            // 8 channels per lane

  int rs = row_start[n];
  int deg = row_start[n + 1] - rs;
  const float* pp = pH + (size_t)h * ETOT + rs;
  const int*   sp = srcs + rs;
  const unsigned short* xp = xlbf + c0;

  float a0 = 0.f, a1 = 0.f, a2 = 0.f, a3 = 0.f;
  float a4 = 0.f, a5 = 0.f, a6 = 0.f, a7 = 0.f;
#pragma unroll 4
  for (int i = 0; i < deg; ++i) {
    int s = sp[i];
    float a = pp[i];
    uint4 v = *(const uint4*)(xp + ((size_t)s << 9));
    a0 = fmaf(bflo(v.x), a, a0);
    a1 = fmaf(bfhi(v.x), a, a1);
    a2 = fmaf(bflo(v.y), a, a2);
    a3 = fmaf(bfhi(v.y), a, a3);
    a4 = fmaf(bflo(v.z), a, a4);
    a5 = fmaf(bfhi(v.z), a, a5);
    a6 = fmaf(bflo(v.w), a, a6);
    a7 = fmaf(bfhi(v.w), a, a7);
  }
  float r = rS[n * 4 + h];
  float4 bv0 = *(const float4*)(bias + c0);
  float4 bv1 = *(const float4*)(bias + c0 + 4);
  f32x4 o0 = { fmaf(a0, r, bv0.x), fmaf(a1, r, bv0.y), fmaf(a2, r, bv0.z), fmaf(a3, r, bv0.w) };
  f32x4 o1 = { fmaf(a4, r, bv1.x), fmaf(a5, r, bv1.y), fmaf(a6, r, bv1.z), fmaf(a7, r, bv1.w) };
  float* op = out + (size_t)n * 512 + c0;
  __builtin_nontemporal_store(o0, (f32x4*)op);
  __builtin_nontemporal_store(o1, (f32x4*)(op + 4));
}

// ---------------- column stats (sum, sumsq) ----------------
__global__ __launch_bounds__(512) void k_stats(const float* __restrict__ hdat,
                                               float* __restrict__ sums) {
  int t = threadIdx.x;
  int r0 = blockIdx.x * 64;
  int r1 = min(r0 + 64, N_NODES);
  float s = 0.f, q = 0.f;
  for (int r = r0; r < r1; ++r) {
    float v = hdat[(size_t)r * 512 + t];
    s += v; q = fmaf(v, v, q);
  }
  atomicAdd(&sums[t], s);
  atomicAdd(&sums[512 + t], q);
}

// ---------------- BN + LeakyReLU(0.01) -> bf16 ----------------
__global__ void k_bn_act(const float* __restrict__ hdat, unsigned short* __restrict__ hbf,
                         const float* __restrict__ stats,
                         const float* __restrict__ g, const float* __restrict__ b) {
  int i = blockIdx.x * blockDim.x + threadIdx.x;
  if (i >= N_NODES * 512) return;
  int c = i & 511;
  const float invN = 1.f / N_NODES;
  float mu = stats[c] * invN;
  float var = stats[512 + c] * invN - mu * mu;
  float y = (hdat[i] - mu) * rsqrtf(var + 1e-5f) * g[c] + b[c];
  y = (y >= 0.f) ? y : 0.01f * y;
  hbf[i] = f2bf(y);
}

// BN + act + residual (bf16 h1) -> bf16
__global__ void k_bn_act_res(const float* __restrict__ hdat, const unsigned short* __restrict__ hprev,
                             unsigned short* __restrict__ hbf,
                             const float* __restrict__ stats,
                             const float* __restrict__ g, const float* __restrict__ b) {
  int i = blockIdx.x * blockDim.x + threadIdx.x;
  if (i >= N_NODES * 512) return;
  int c = i & 511;
  const float invN = 1.f / N_NODES;
  float mu = stats[c] * invN;
  float var = stats[512 + c] * invN - mu * mu;
  float y = (hdat[i] - mu) * rsqrtf(var + 1e-5f) * g[c] + b[c];
  y = (y >= 0.f) ? y : 0.01f * y;
  hbf[i] = f2bf(y + bf2f(hprev[i]));
}

extern "C" void kernel_launch(void* const* d_in, const int* in_sizes, int n_in,
                              void* d_out, int out_size, void* d_ws, size_t ws_size,
                              hipStream_t stream) {
  const float* X      = (const float*)d_in[0];
  const int*   ei     = (const int*)d_in[1];
  const float* pos    = (const float*)d_in[3];
  const float* W1     = (const float*)d_in[4];
  const float* a_src1 = (const float*)d_in[5];
  const float* a_dst1 = (const float*)d_in[6];
  const float* b1     = (const float*)d_in[7];
  const float* W2     = (const float*)d_in[8];
  const float* a_src2 = (const float*)d_in[9];
  const float* a_dst2 = (const float*)d_in[10];
  const float* b2     = (const float*)d_in[11];
  const float* bn1_g  = (const float*)d_in[12];
  const float* bn1_b  = (const float*)d_in[13];
  const float* bn2_g  = (const float*)d_in[14];
  const float* bn2_b  = (const float*)d_in[15];
  const float* out_W  = (const float*)d_in[18];
  const float* out_b  = (const float*)d_in[19];
  float* out = (float*)d_out;

  float* ws = (float*)d_ws;
  size_t o = 0;
  float* agg   = ws + o; o += (size_t)N_NODES * 512;   // 41 MB fp32 (pre-BN, both layers)
  float* alS   = ws + o; o += (size_t)N_NODES * 4;
  float* alD   = ws + o; o += (size_t)N_NODES * 4;
  float* rS    = ws + o; o += (size_t)N_NODES * 4;     // per-node 1/sum(p) per head
  float* stats = ws + o; o += 2048;
  unsigned short* xlbf = (unsigned short*)(ws + o); o += (size_t)N_NODES * 256;  // GEMM out (both layers)
  unsigned short* xbf  = (unsigned short*)(ws + o); o += (size_t)N_NODES * 64;   // input bf16
  unsigned short* hbf  = (unsigned short*)(ws + o); o += (size_t)N_NODES * 256;  // h1 bf16 (GEMM2 in + residual)
  unsigned short* h2bf = (unsigned short*)(ws + o); o += (size_t)N_NODES * 256;  // h2 bf16 (out-proj in)
  unsigned short* W1t  = (unsigned short*)(ws + o); o += 128 * 512 / 2;
  unsigned short* W2t  = (unsigned short*)(ws + o); o += 512 * 512 / 2;
  unsigned short* oWt  = (unsigned short*)(ws + o); o += 512 * 256 / 2;
  int* ip = (int*)(ws + o);
  int* counts    = ip; ip += N_NODES;
  int* row_start = ip; ip += N_NODES + 1;
  int* wcur      = ip; ip += N_NODES;
  int* srcs      = ip; ip += ETOT;
  int* perm      = ip; ip += N_NODES;
  int* escan     = ip; ip += N_NODES;
  int* bsum      = ip; ip += SCAN_B;
  int* bbase     = ip; ip += SCAN_B;
  int* ghist     = ip; ip += 64;
  int* gcur      = ip; ip += 64;
  // pH [4][ETOT] fp32 (5.44 MB) aliases h2bf (20.5 MB): h2bf is first written
  // by k_bn_act_res, strictly after the last pH read (layer-2 k_agg).
  float* pH = (float*)h2bf;

  // CSR by dst (self loops included) + deg-bucket perm + input prep.
  // Scan is 3-phase multi-block (the old 1-block k_scan was 47 us of pure
  // single-CU latency); degree counting-sort is folded into the same phases.
  k_init   <<<(N_NODES + 255) / 256, 256, 0, stream>>>(counts, stats, ghist, row_start);
  k_hist   <<<(N_EDGES + 255) / 256, 256, 0, stream>>>(ei, counts);
  k_scan1  <<<SCAN_B, 256, 0, stream>>>(counts, escan, bsum, ghist);
  k_scan2  <<<1, 128, 0, stream>>>(bsum, bbase, ghist, gcur);
  k_scan3  <<<SCAN_B, 256, 0, stream>>>(counts, escan, bbase, row_start, wcur, srcs, gcur, perm);
  k_scatter<<<(N_EDGES + 255) / 256, 256, 0, stream>>>(ei, wcur, srcs);
  k_prep   <<<(N_NODES * 128 + 255) / 256, 256, 0, stream>>>(X, pos, xbf, W1, W2, out_W, W1t, W2t, oWt);

  dim3 gagg(8, N_NODES / 32);   // 8 slices x 625

  // ---- layer 1 ----
  { dim3 g(512 / 128, (N_NODES + 127) / 128);
    k_mgemm<<<g, 256, 0, stream>>>(xbf, W1t, nullptr, nullptr, xlbf, N_NODES, 512, 128); }
  k_al   <<<N_NODES, 256, 0, stream>>>(xlbf, a_src1, a_dst1, alS, alD);
  k_alpha<<<(N_NODES + 3) / 4, 256, 0, stream>>>(alS, alD, row_start, srcs, pH, rS);
  k_agg  <<<gagg, 256, 0, stream>>>(xlbf, pH, rS, row_start, srcs, perm, b1, agg);
  k_stats<<<(N_NODES + 63) / 64, 512, 0, stream>>>(agg, stats);
  k_bn_act<<<(N_NODES * 512 + 255) / 256, 256, 0, stream>>>(agg, hbf, stats, bn1_g, bn1_b);
  // ---- layer 2 ----
  { dim3 g(512 / 128, (N_NODES + 127) / 128);
    k_mgemm<<<g, 256, 0, stream>>>(hbf, W2t, nullptr, nullptr, xlbf, N_NODES, 512, 512); }
  k_al   <<<N_NODES, 256, 0, stream>>>(xlbf, a_src2, a_dst2, alS, alD);
  k_alpha<<<(N_NODES + 3) / 4, 256, 0, stream>>>(alS, alD, row_start, srcs, pH, rS);
  k_agg  <<<gagg, 256, 0, stream>>>(xlbf, pH, rS, row_start, srcs, perm, b2, agg);
  k_stats<<<(N_NODES + 63) / 64, 512, 0, stream>>>(agg, stats + 1024);
  k_bn_act_res<<<(N_NODES * 512 + 255) / 256, 256, 0, stream>>>(agg, hbf, h2bf, stats + 1024, bn2_g, bn2_b);
  // ---- output projection ----
  { dim3 g(256 / 128, (N_NODES + 127) / 128);
    k_mgemm<<<g, 256, 0, stream>>>(h2bf, oWt, out_b, out, nullptr, N_NODES, 256, 512); }
}

// Round 4
// 446.918 us; speedup vs baseline: 1.2265x; 1.2265x over previous
//
#include <hip/hip_runtime.h>
#include <hip/hip_bf16.h>
#include <math.h>

#define N_NODES 20000
#define N_EDGES 320000
#define F_IN    127
#define ETOT    (N_EDGES + N_NODES)
#define SCAN_B  ((N_NODES + 255) / 256)   // 79

typedef __attribute__((ext_vector_type(8))) short short8;
typedef __attribute__((ext_vector_type(4))) float f32x4;

__device__ inline unsigned short f2bf(float f) {
  union { float f; unsigned int u; } v; v.f = f;
  unsigned int u = v.u;
  unsigned int r = (u + 0x7fffu + ((u >> 16) & 1u)) >> 16;
  return (unsigned short)r;
}
__device__ inline float bf2f(unsigned short b) {
  union { unsigned int u; float f; } v; v.u = ((unsigned int)b) << 16;
  return v.f;
}
__device__ inline float bflo(unsigned int v) {
  union { unsigned int u; float f; } x; x.u = v << 16; return x.f;
}
__device__ inline float bfhi(unsigned int v) {
  union { unsigned int u; float f; } x; x.u = v & 0xffff0000u; return x.f;
}

// ---------------- CSR build ----------------
__global__ void k_init(int* __restrict__ counts, float* __restrict__ stats,
                       int* __restrict__ row_start) {
  int i = blockIdx.x * blockDim.x + threadIdx.x;
  if (i < N_NODES) counts[i] = 1;   // self loop pre-counted
  if (i < 2048) stats[i] = 0.f;
  if (i == 0) row_start[N_NODES] = ETOT;   // total is a compile-time constant
}

__global__ void k_hist(const int* __restrict__ ei, int* __restrict__ counts) {
  int e = blockIdx.x * blockDim.x + threadIdx.x;
  if (e < N_EDGES) atomicAdd(&counts[ei[N_EDGES + e]], 1);
}

// ---- multi-block scan, phase 1: per-block exclusive scan + block sums ----
// Degree histogram is LDS-local (global same-address atomics across blocks
// cost ~50us for 20K ops on ~25 hot buckets; LDS atomics are ~free).
// Per-block partials go to bhist[block][64] with plain stores.
__global__ __launch_bounds__(256) void k_scan1(const int* __restrict__ counts,
                                               int* __restrict__ escan,
                                               int* __restrict__ bsum,
                                               int* __restrict__ bhist) {
  __shared__ int sh[256];
  __shared__ int lh[64];
  int t = threadIdx.x;
  if (t < 64) lh[t] = 0;
  __syncthreads();
  int i = blockIdx.x * 256 + t;
  int c = (i < N_NODES) ? counts[i] : 0;
  if (i < N_NODES) atomicAdd(&lh[min(c, 63)], 1);
  sh[t] = c;
  __syncthreads();
#pragma unroll
  for (int off = 1; off < 256; off <<= 1) {
    int u = (t >= off) ? sh[t - off] : 0;
    __syncthreads();
    sh[t] += u;
    __syncthreads();
  }
  if (i < N_NODES) escan[i] = sh[t] - c;
  if (t == 255) bsum[blockIdx.x] = sh[255];
  if (t < 64) bhist[blockIdx.x * 64 + t] = lh[t];   // lh complete: scan barriers above
}

// ---- phase 2 (tiny, 1 block): scan block sums + per-block bucket cursors ----
// bboff[b][d] = global base of bucket d + sum of bucket-d partials of blocks < b.
__global__ __launch_bounds__(128) void k_scan2(const int* __restrict__ bsum,
                                               int* __restrict__ bbase,
                                               const int* __restrict__ bhist,
                                               int* __restrict__ bboff) {
  __shared__ int sh[128];
  int t = threadIdx.x;
  int v = (t < SCAN_B) ? bsum[t] : 0;
  sh[t] = v;
  __syncthreads();
#pragma unroll
  for (int off = 1; off < 128; off <<= 1) {
    int u = (t >= off) ? sh[t - off] : 0;
    __syncthreads();
    sh[t] += u;
    __syncthreads();
  }
  if (t < SCAN_B) bbase[t] = sh[t] - v;
  __syncthreads();
  // bucket totals across blocks
  int tot = 0;
  if (t < 64) {
    for (int b = 0; b < SCAN_B; ++b) tot += bhist[b * 64 + t];
  }
  sh[t] = (t < 64) ? tot : 0;
  __syncthreads();
#pragma unroll
  for (int off = 1; off < 64; off <<= 1) {
    int u = (t >= off) ? sh[t - off] : 0;
    __syncthreads();
    sh[t] += u;
    __syncthreads();
  }
  if (t < 64) {
    int run = sh[t] - tot;   // exclusive bucket base
    for (int b = 0; b < SCAN_B; ++b) {
      bboff[b * 64 + t] = run;
      run += bhist[b * 64 + t];
    }
  }
}

// ---- phase 3: finalize row_start / self-loop / write cursors + perm scatter ----
// Perm scatter uses LDS cursors seeded from bboff (no global atomics).
__global__ __launch_bounds__(256) void k_scan3(const int* __restrict__ counts,
                                               const int* __restrict__ escan,
                                               const int* __restrict__ bbase,
                                               int* __restrict__ row_start,
                                               int* __restrict__ wcur,
                                               int* __restrict__ srcs,
                                               const int* __restrict__ bboff,
                                               int* __restrict__ perm) {
  __shared__ int cur[64];
  int t = threadIdx.x;
  if (t < 64) cur[t] = bboff[blockIdx.x * 64 + t];
  __syncthreads();
  int i = blockIdx.x * 256 + t;
  if (i >= N_NODES) return;
  int rs = bbase[blockIdx.x] + escan[i];
  row_start[i] = rs;
  srcs[rs] = i;          // self loop at slot 0 of each row
  wcur[i] = rs + 1;
  int d = min(counts[i], 63);
  int p = atomicAdd(&cur[d], 1);
  perm[p] = i;           // degree-bucketed permutation (within-bucket order arbitrary)
}

__global__ void k_scatter(const int* __restrict__ ei, int* __restrict__ wcur,
                          int* __restrict__ srcs) {
  int e = blockIdx.x * blockDim.x + threadIdx.x;
  if (e < N_EDGES) {
    int s = ei[e], d = ei[N_EDGES + e];
    int p = atomicAdd(&wcur[d], 1);
    srcs[p] = s;
  }
}

// ---------------- input concat + weight cast/transpose (merged) ----------------
__global__ void k_prep(const float* __restrict__ X, const float* __restrict__ pos,
                       unsigned short* __restrict__ xbf,
                       const float* __restrict__ W1, const float* __restrict__ W2,
                       const float* __restrict__ oW,
                       unsigned short* __restrict__ W1t, unsigned short* __restrict__ W2t,
                       unsigned short* __restrict__ oWt) {
  int i = blockIdx.x * blockDim.x + threadIdx.x;
  if (i < N_NODES * 128) { int n = i >> 7, k = i & 127; xbf[i] = f2bf((k < F_IN) ? X[n * F_IN + k] : pos[n]); }
  if (i < 128 * 512) { int r = i >> 9, c = i & 511; W1t[c * 128 + r] = f2bf(W1[i]); }
  if (i < 512 * 512) { int r = i >> 9, c = i & 511; W2t[c * 512 + r] = f2bf(W2[i]); }
  if (i < 512 * 256) { int r = i >> 8, c = i & 255; oWt[c * 512 + r] = f2bf(oW[i]); }
}

// ---------------- bf16 MFMA GEMM: C = A[M,K] @ Bt[Nc,K]^T (+bias) ----------------
// 128x128 tile, 256 thr (4 waves, 2x2), each wave 64x64 = 4x4 MFMA 16x16x32.
__global__ __launch_bounds__(256) void k_mgemm(
    const unsigned short* __restrict__ A, const unsigned short* __restrict__ Bt,
    const float* __restrict__ bias, float* __restrict__ Cf,
    unsigned short* __restrict__ Cbf, int M, int Nc, int K)
{
  __shared__ unsigned short As[128 * 32];
  __shared__ unsigned short Bs[128 * 32];
  int t = threadIdx.x;
  int w = t >> 6, l = t & 63;
  int wr = w >> 1, wc = w & 1;
  int lane15 = l & 15, kq = l >> 4;
  int m0 = blockIdx.y * 128, n0 = blockIdx.x * 128;
  f32x4 acc[4][4] = {};

  int cA = 2 * w;
  int rowA0 = 16 * cA + (l >> 2);
  int koff = (l & 3) * 8;

  for (int k0 = 0; k0 < K; k0 += 32) {
    __syncthreads();
#pragma unroll
    for (int cc = 0; cc < 2; ++cc) {
      int c = cA + cc;
      int row = rowA0 + 16 * cc;
      const unsigned short* g = A + (size_t)min(m0 + row, M - 1) * K + k0 + koff;
      __builtin_amdgcn_global_load_lds(
          (const __attribute__((address_space(1))) unsigned int*)g,
          (__attribute__((address_space(3))) unsigned int*)&As[c * 512], 16, 0, 0);
      const unsigned short* gb = Bt + (size_t)(n0 + row) * K + k0 + koff;
      __builtin_amdgcn_global_load_lds(
          (const __attribute__((address_space(1))) unsigned int*)gb,
          (__attribute__((address_space(3))) unsigned int*)&Bs[c * 512], 16, 0, 0);
    }
    __syncthreads();
    short8 a[4], b[4];
#pragma unroll
    for (int i = 0; i < 4; ++i)
      a[i] = *(const short8*)&As[(wr * 64 + i * 16 + lane15) * 32 + kq * 8];
#pragma unroll
    for (int j = 0; j < 4; ++j)
      b[j] = *(const short8*)&Bs[(wc * 64 + j * 16 + lane15) * 32 + kq * 8];
#pragma unroll
    for (int i = 0; i < 4; ++i)
#pragma unroll
      for (int j = 0; j < 4; ++j)
        acc[i][j] = __builtin_amdgcn_mfma_f32_16x16x32_bf16(a[i], b[j], acc[i][j], 0, 0, 0);
  }
  // epilogue: C/D layout col=lane&15, row=(lane>>4)*4+reg
#pragma unroll
  for (int i = 0; i < 4; ++i) {
#pragma unroll
    for (int j = 0; j < 4; ++j) {
      int col = n0 + wc * 64 + j * 16 + lane15;
      float bv = bias ? bias[col] : 0.f;
#pragma unroll
      for (int r = 0; r < 4; ++r) {
        int row = m0 + wr * 64 + i * 16 + kq * 4 + r;
        if (row < M) {
          float val = acc[i][j][r] + bv;
          if (Cbf) Cbf[(size_t)row * Nc + col] = f2bf(val);
          else     Cf[(size_t)row * Nc + col] = val;
        }
      }
    }
  }
}

// ---------------- attention logit vectors al_s/al_d [N,4], bf16 input ----------------
__global__ __launch_bounds__(256) void k_al(
    const unsigned short* __restrict__ xlbf, const float* __restrict__ a_src,
    const float* __restrict__ a_dst, float* __restrict__ al_s, float* __restrict__ al_d)
{
  int n = blockIdx.x, t = threadIdx.x;
  int h = t >> 6, l = t & 63;
  int c0 = h * 128 + 2 * l;
  unsigned int v = *(const unsigned int*)&xlbf[(size_t)n * 512 + c0];
  float v0 = bflo(v), v1 = bfhi(v);
  float ps = v0 * a_src[c0] + v1 * a_src[c0 + 1];
  float pd = v0 * a_dst[c0] + v1 * a_dst[c0 + 1];
#pragma unroll
  for (int off = 32; off; off >>= 1) { ps += __shfl_down(ps, off); pd += __shfl_down(pd, off); }
  if (l == 0) { al_s[n * 4 + h] = ps; al_d[n * 4 + h] = pd; }
}

// ---------------- edge softmax, single pass, no max-subtraction ----------------
// Softmax is shift-invariant; logits here are O(1) (clamped at 60 for safety,
// self-loop guarantees S>0), so skip the max pass entirely. Writes UNNORMALIZED
// p=exp(lg) head-major pH[h][e] (stream-read by k_agg) and per-node 1/S in rS.
// k_agg multiplies its accumulator by 1/S at the end.
// Block 256 = 4 waves; wave per node, 64 lanes stride edges.
__global__ __launch_bounds__(256) void k_alpha(
    const float* __restrict__ al_s, const float* __restrict__ al_d,
    const int* __restrict__ row_start, const int* __restrict__ srcs,
    float* __restrict__ pH, float* __restrict__ rS)
{
  int w = threadIdx.x >> 6, l = threadIdx.x & 63;
  int n = blockIdx.x * 4 + w;
  if (n >= N_NODES) return;

  int rs = row_start[n];
  int deg = row_start[n + 1] - rs;
  float4 ad4 = *(const float4*)&al_d[n * 4];
  float s0 = 0.f, s1 = 0.f, s2 = 0.f, s3 = 0.f;
  for (int i = l; i < deg; i += 64) {
    int e = rs + i;
    int s = srcs[e];
    float4 as4 = *(const float4*)&al_s[(size_t)s * 4];
    float lg0 = as4.x + ad4.x; lg0 = (lg0 >= 0.f) ? lg0 : 0.2f * lg0;
    float lg1 = as4.y + ad4.y; lg1 = (lg1 >= 0.f) ? lg1 : 0.2f * lg1;
    float lg2 = as4.z + ad4.z; lg2 = (lg2 >= 0.f) ? lg2 : 0.2f * lg2;
    float lg3 = as4.w + ad4.w; lg3 = (lg3 >= 0.f) ? lg3 : 0.2f * lg3;
    float p0 = __expf(fminf(lg0, 60.f));
    float p1 = __expf(fminf(lg1, 60.f));
    float p2 = __expf(fminf(lg2, 60.f));
    float p3 = __expf(fminf(lg3, 60.f));
    pH[0 * ETOT + e] = p0;
    pH[1 * ETOT + e] = p1;
    pH[2 * ETOT + e] = p2;
    pH[3 * ETOT + e] = p3;
    s0 += p0; s1 += p1; s2 += p2; s3 += p3;
  }
#pragma unroll
  for (int off = 32; off; off >>= 1) {
    s0 += __shfl_down(s0, off);
    s1 += __shfl_down(s1, off);
    s2 += __shfl_down(s2, off);
    s3 += __shfl_down(s3, off);
  }
  if (l == 0) {
    rS[n * 4 + 0] = 1.f / (s0 + 1e-16f);
    rS[n * 4 + 1] = 1.f / (s1 + 1e-16f);
    rS[n * 4 + 2] = 1.f / (s2 + 1e-16f);
    rS[n * 4 + 3] = 1.f / (s3 + 1e-16f);
  }
}

// ---------------- GAT aggregate: channel-sliced + deg-sorted ----------------
// Grid (8, 625): blockIdx.x = channel slice (64 ch) -> pinned to one XCD by
// round-robin dispatch; per-XCD gather working set 2.56 MB < 4 MB L2.
// Block 256 = 4 waves; wave = 8 nodes x 8 lanes; lane owns 8 ch (16B uint4
// gather) -> 8 independent gather chains per wave. Nodes taken via deg-sorted
// perm so the 8 nodes of a wave have ~equal degree (uniform trip count).
// Accumulates unnormalized sum(p*x), scales by 1/S at the end.
__global__ __launch_bounds__(256) void k_agg(
    const unsigned short* __restrict__ xlbf, const float* __restrict__ pH,
    const float* __restrict__ rS, const int* __restrict__ row_start,
    const int* __restrict__ srcs, const int* __restrict__ perm,
    const float* __restrict__ bias, float* __restrict__ out)
{
  int slice = blockIdx.x;                 // 0..7
  int t = threadIdx.x;
  int w = t >> 6;                         // wave in block
  int l = t & 63;
  int grp = l >> 3;                       // 0..7 node within wave
  int g = l & 7;                          // lane within group
  int n = perm[(blockIdx.y * 4 + w) * 8 + grp];   // 625*4*8 == 20000 exactly
  int h = slice >> 1;                     // head owning this slice
  int c0 = slice * 64 + g * 8;            // 8 channels per lane

  int rs = row_start[n];
  int deg = row_start[n + 1] - rs;
  const float* pp = pH + (size_t)h * ETOT + rs;
  const int*   sp = srcs + rs;
  const unsigned short* xp = xlbf + c0;

  float a0 = 0.f, a1 = 0.f, a2 = 0.f, a3 = 0.f;
  float a4 = 0.f, a5 = 0.f, a6 = 0.f, a7 = 0.f;
#pragma unroll 4
  for (int i = 0; i < deg; ++i) {
    int s = sp[i];
    float a = pp[i];
    uint4 v = *(const uint4*)(xp + ((size_t)s << 9));
    a0 = fmaf(bflo(v.x), a, a0);
    a1 = fmaf(bfhi(v.x), a, a1);
    a2 = fmaf(bflo(v.y), a, a2);
    a3 = fmaf(bfhi(v.y), a, a3);
    a4 = fmaf(bflo(v.z), a, a4);
    a5 = fmaf(bfhi(v.z), a, a5);
    a6 = fmaf(bflo(v.w), a, a6);
    a7 = fmaf(bfhi(v.w), a, a7);
  }
  float r = rS[n * 4 + h];
  float4 bv0 = *(const float4*)(bias + c0);
  float4 bv1 = *(const float4*)(bias + c0 + 4);
  f32x4 o0 = { fmaf(a0, r, bv0.x), fmaf(a1, r, bv0.y), fmaf(a2, r, bv0.z), fmaf(a3, r, bv0.w) };
  f32x4 o1 = { fmaf(a4, r, bv1.x), fmaf(a5, r, bv1.y), fmaf(a6, r, bv1.z), fmaf(a7, r, bv1.w) };
  float* op = out + (size_t)n * 512 + c0;
  __builtin_nontemporal_store(o0, (f32x4*)op);
  __builtin_nontemporal_store(o1, (f32x4*)(op + 4));
}

// ---------------- column stats (sum, sumsq) ----------------
__global__ __launch_bounds__(512) void k_stats(const float* __restrict__ hdat,
                                               float* __restrict__ sums) {
  int t = threadIdx.x;
  int r0 = blockIdx.x * 64;
  int r1 = min(r0 + 64, N_NODES);
  float s = 0.f, q = 0.f;
  for (int r = r0; r < r1; ++r) {
    float v = hdat[(size_t)r * 512 + t];
    s += v; q = fmaf(v, v, q);
  }
  atomicAdd(&sums[t], s);
  atomicAdd(&sums[512 + t], q);
}

// ---------------- BN + LeakyReLU(0.01) -> bf16 ----------------
__global__ void k_bn_act(const float* __restrict__ hdat, unsigned short* __restrict__ hbf,
                         const float* __restrict__ stats,
                         const float* __restrict__ g, const float* __restrict__ b) {
  int i = blockIdx.x * blockDim.x + threadIdx.x;
  if (i >= N_NODES * 512) return;
  int c = i & 511;
  const float invN = 1.f / N_NODES;
  float mu = stats[c] * invN;
  float var = stats[512 + c] * invN - mu * mu;
  float y = (hdat[i] - mu) * rsqrtf(var + 1e-5f) * g[c] + b[c];
  y = (y >= 0.f) ? y : 0.01f * y;
  hbf[i] = f2bf(y);
}

// BN + act + residual (bf16 h1) -> bf16
__global__ void k_bn_act_res(const float* __restrict__ hdat, const unsigned short* __restrict__ hprev,
                             unsigned short* __restrict__ hbf,
                             const float* __restrict__ stats,
                             const float* __restrict__ g, const float* __restrict__ b) {
  int i = blockIdx.x * blockDim.x + threadIdx.x;
  if (i >= N_NODES * 512) return;
  int c = i & 511;
  const float invN = 1.f / N_NODES;
  float mu = stats[c] * invN;
  float var = stats[512 + c] * invN - mu * mu;
  float y = (hdat[i] - mu) * rsqrtf(var + 1e-5f) * g[c] + b[c];
  y = (y >= 0.f) ? y : 0.01f * y;
  hbf[i] = f2bf(y + bf2f(hprev[i]));
}

extern "C" void kernel_launch(void* const* d_in, const int* in_sizes, int n_in,
                              void* d_out, int out_size, void* d_ws, size_t ws_size,
                              hipStream_t stream) {
  const float* X      = (const float*)d_in[0];
  const int*   ei     = (const int*)d_in[1];
  const float* pos    = (const float*)d_in[3];
  const float* W1     = (const float*)d_in[4];
  const float* a_src1 = (const float*)d_in[5];
  const float* a_dst1 = (const float*)d_in[6];
  const float* b1     = (const float*)d_in[7];
  const float* W2     = (const float*)d_in[8];
  const float* a_src2 = (const float*)d_in[9];
  const float* a_dst2 = (const float*)d_in[10];
  const float* b2     = (const float*)d_in[11];
  const float* bn1_g  = (const float*)d_in[12];
  const float* bn1_b  = (const float*)d_in[13];
  const float* bn2_g  = (const float*)d_in[14];
  const float* bn2_b  = (const float*)d_in[15];
  const float* out_W  = (const float*)d_in[18];
  const float* out_b  = (const float*)d_in[19];
  float* out = (float*)d_out;

  float* ws = (float*)d_ws;
  size_t o = 0;
  float* agg   = ws + o; o += (size_t)N_NODES * 512;   // 41 MB fp32 (pre-BN, both layers)
  float* alS   = ws + o; o += (size_t)N_NODES * 4;
  float* alD   = ws + o; o += (size_t)N_NODES * 4;
  float* rS    = ws + o; o += (size_t)N_NODES * 4;     // per-node 1/sum(p) per head
  float* stats = ws + o; o += 2048;
  unsigned short* xlbf = (unsigned short*)(ws + o); o += (size_t)N_NODES * 256;  // GEMM out (both layers)
  unsigned short* xbf  = (unsigned short*)(ws + o); o += (size_t)N_NODES * 64;   // input bf16
  unsigned short* hbf  = (unsigned short*)(ws + o); o += (size_t)N_NODES * 256;  // h1 bf16 (GEMM2 in + residual)
  unsigned short* h2bf = (unsigned short*)(ws + o); o += (size_t)N_NODES * 256;  // h2 bf16 (out-proj in)
  unsigned short* W1t  = (unsigned short*)(ws + o); o += 128 * 512 / 2;
  unsigned short* W2t  = (unsigned short*)(ws + o); o += 512 * 512 / 2;
  unsigned short* oWt  = (unsigned short*)(ws + o); o += 512 * 256 / 2;
  int* ip = (int*)(ws + o);
  int* counts    = ip; ip += N_NODES;
  int* row_start = ip; ip += N_NODES + 1;
  int* wcur      = ip; ip += N_NODES;
  int* srcs      = ip; ip += ETOT;
  int* perm      = ip; ip += N_NODES;
  int* escan     = ip; ip += N_NODES;
  int* bsum      = ip; ip += SCAN_B;
  int* bbase     = ip; ip += SCAN_B;
  int* bhist     = ip; ip += SCAN_B * 64;
  int* bboff     = ip; ip += SCAN_B * 64;
  // pH [4][ETOT] fp32 (5.44 MB) aliases h2bf (20.5 MB): h2bf is first written
  // by k_bn_act_res, strictly after the last pH read (layer-2 k_agg).
  float* pH = (float*)h2bf;

  // CSR by dst (self loops included) + deg-bucket perm + input prep.
  // 3-phase multi-block scan; ALL histogram/cursor atomics are LDS-local
  // (global same-address atomics over ~25 hot buckets measured ~50us/20K ops).
  k_init   <<<(N_NODES + 255) / 256, 256, 0, stream>>>(counts, stats, row_start);
  k_hist   <<<(N_EDGES + 255) / 256, 256, 0, stream>>>(ei, counts);
  k_scan1  <<<SCAN_B, 256, 0, stream>>>(counts, escan, bsum, bhist);
  k_scan2  <<<1, 128, 0, stream>>>(bsum, bbase, bhist, bboff);
  k_scan3  <<<SCAN_B, 256, 0, stream>>>(counts, escan, bbase, row_start, wcur, srcs, bboff, perm);
  k_scatter<<<(N_EDGES + 255) / 256, 256, 0, stream>>>(ei, wcur, srcs);
  k_prep   <<<(N_NODES * 128 + 255) / 256, 256, 0, stream>>>(X, pos, xbf, W1, W2, out_W, W1t, W2t, oWt);

  dim3 gagg(8, N_NODES / 32);   // 8 slices x 625

  // ---- layer 1 ----
  { dim3 g(512 / 128, (N_NODES + 127) / 128);
    k_mgemm<<<g, 256, 0, stream>>>(xbf, W1t, nullptr, nullptr, xlbf, N_NODES, 512, 128); }
  k_al   <<<N_NODES, 256, 0, stream>>>(xlbf, a_src1, a_dst1, alS, alD);
  k_alpha<<<(N_NODES + 3) / 4, 256, 0, stream>>>(alS, alD, row_start, srcs, pH, rS);
  k_agg  <<<gagg, 256, 0, stream>>>(xlbf, pH, rS, row_start, srcs, perm, b1, agg);
  k_stats<<<(N_NODES + 63) / 64, 512, 0, stream>>>(agg, stats);
  k_bn_act<<<(N_NODES * 512 + 255) / 256, 256, 0, stream>>>(agg, hbf, stats, bn1_g, bn1_b);
  // ---- layer 2 ----
  { dim3 g(512 / 128, (N_NODES + 127) / 128);
    k_mgemm<<<g, 256, 0, stream>>>(hbf, W2t, nullptr, nullptr, xlbf, N_NODES, 512, 512); }
  k_al   <<<N_NODES, 256, 0, stream>>>(xlbf, a_src2, a_dst2, alS, alD);
  k_alpha<<<(N_NODES + 3) / 4, 256, 0, stream>>>(alS, alD, row_start, srcs, pH, rS);
  k_agg  <<<gagg, 256, 0, stream>>>(xlbf, pH, rS, row_start, srcs, perm, b2, agg);
  k_stats<<<(N_NODES + 63) / 64, 512, 0, stream>>>(agg, stats + 1024);
  k_bn_act_res<<<(N_NODES * 512 + 255) / 256, 256, 0, stream>>>(agg, hbf, h2bf, stats + 1024, bn2_g, bn2_b);
  // ---- output projection ----
  { dim3 g(256 / 128, (N_NODES + 127) / 128);
    k_mgemm<<<g, 256, 0, stream>>>(h2bf, oWt, out_b, out, nullptr, N_NODES, 256, 512); }
}